// Round 1
// baseline (1826.101 us; speedup 1.0000x reference)
//
#include <hip/hip_runtime.h>
#include <math.h>

// RecurrentSlotEncoder: B=16,K=16,N=1024,D=256,L=8
// Key algebra: scores = (Q@Wk) @ h^T  (no K-projection of h!)
//              gi     = (attn@h) @ (W_ih@Wv)^T + (b_ih + W_ih@bv)  (no V-projection!)
// => per-step heavy work is only: scores dot (L x N x D) and attn@h (L x N x D).
// H is read exactly once per step (staged in LDS, used for both scores and AV).

#define Bn 16
#define KK 16
#define Nn 1024
#define Dn 256
#define Ln 8

// workspace float offsets
#define OFF_WQK   0          // 256*256
#define OFF_BQK   65536      // 256
#define OFF_WGI   65792      // 768*256
#define OFF_BGI   262400     // 768
#define OFF_SLOTS 263168     // 128*256
#define OFF_QK    295936     // 128*256
#define OFF_PAV   328704     // 16*16*8*256
#define OFF_PDEN  852992     // 16*16*8
#define OFF_S2    855040     // 128*256
#define OFF_F1    887808     // 128*256
#define OFF_X     920576     // 128*256
#define OFF_XSUM  953344     // 128
#define OFF_XSQ   953472     // 128

__global__ __launch_bounds__(256) void precompute_kernel(
    const float* __restrict__ Wq, const float* __restrict__ bq, const float* __restrict__ Wk,
    const float* __restrict__ Wih, const float* __restrict__ bih,
    const float* __restrict__ Wv, const float* __restrict__ bv,
    float* __restrict__ Wqk, float* __restrict__ bqk,
    float* __restrict__ Wgi, float* __restrict__ bgi) {
  int w = blockIdx.x, tid = threadIdx.x;
  if (w < 256) {
    // Wqk[d=w][e=tid] = sum_a Wq[a][w] * Wk[a][tid]
    float acc = 0.f;
    for (int a = 0; a < 256; ++a) acc += Wq[a * 256 + w] * Wk[a * 256 + tid];
    Wqk[w * 256 + tid] = acc;
  } else if (w < 1024) {
    int jj = w - 256;  // Wgi[jj][d=tid] = sum_e Wih[jj][e] * Wv[e][d]
    float acc = 0.f;
    for (int e = 0; e < 256; ++e) acc += Wih[jj * 256 + e] * Wv[e * 256 + tid];
    Wgi[jj * 256 + tid] = acc;
    if (tid == 0) {
      float s = bih[jj];
      for (int e = 0; e < 256; ++e) s += Wih[jj * 256 + e] * bv[e];
      bgi[jj] = s;
    }
  } else {
    float acc = 0.f;
    for (int a = 0; a < 256; ++a) acc += bq[a] * Wk[a * 256 + tid];
    bqk[tid] = acc;
  }
}

__global__ __launch_bounds__(256) void init_slots_kernel(
    const float* __restrict__ eps, const float* __restrict__ mu,
    const float* __restrict__ lsig, float* __restrict__ slots) {
  int idx = blockIdx.x * 256 + threadIdx.x;  // 32768
  int r = idx & 2047;
  slots[idx] = mu[r] + expf(lsig[r]) * eps[idx];
}

// Qk = slots @ Wqk + bqk  (used once at t=0; per-step it is fused into ln_qk)
__global__ __launch_bounds__(256) void qk0_kernel(
    const float* __restrict__ Wqk, const float* __restrict__ bqk,
    const float* __restrict__ slots, float* __restrict__ Qkout) {
  __shared__ float sl_s[2048];
  int j = blockIdx.x & 7, b = blockIdx.x >> 3, tid = threadIdx.x;
  for (int k = 0; k < 8; ++k) sl_s[tid + k * 256] = slots[b * 2048 + tid + k * 256];
  __syncthreads();
  int l = tid >> 5, ee = j * 32 + (tid & 31);
  float acc = bqk[ee];
  for (int d = 0; d < 256; ++d) acc += sl_s[l * 256 + d] * Wqk[d * 256 + ee];
  Qkout[b * 2048 + l * 256 + ee] = acc;
}

// Fused attention: per (b, 64-row tile): scores -> exp (unnormalized Beta),
// partial denom, partial attn@H. H tile staged once in LDS (row stride 258
// => 2-way max bank aliasing in both row- and column-access phases).
__global__ __launch_bounds__(256) void attn_kernel(
    const float* __restrict__ H, const float* __restrict__ Qk,
    float* __restrict__ beta_out, float* __restrict__ par_av,
    float* __restrict__ par_den, int t) {
  __shared__ float h_s[32 * 258];
  __shared__ float qk_s[Ln * Dn];
  __shared__ float e_s[256];
  __shared__ float red[256];
  int tile = blockIdx.x, b = blockIdx.y, tid = threadIdx.x;
  for (int k = 0; k < 8; ++k) qk_s[tid + k * 256] = Qk[b * 2048 + tid + k * 256];
  int l = tid >> 5, row = tid & 31;
  float av[8];
#pragma unroll
  for (int i = 0; i < 8; ++i) av[i] = 0.f;
  float dloc = 0.f;
  const float* Hbase = H + (((long)b * KK + t) * Nn + tile * 64) * Dn;
  for (int sub = 0; sub < 2; ++sub) {
    __syncthreads();  // protect h_s/e_s reuse (also covers qk_s first time)
    const float4* src = (const float4*)(Hbase + sub * 32 * 256);
    for (int k = 0; k < 8; ++k) {
      int idx4 = tid + k * 256;  // 0..2047, coalesced
      int r = idx4 >> 6, d4 = idx4 & 63;
      float4 v = src[idx4];
      float* dst = &h_s[r * 258 + d4 * 4];
      ((float2*)dst)[0] = make_float2(v.x, v.y);
      ((float2*)dst)[1] = make_float2(v.z, v.w);
    }
    __syncthreads();
    // phase A: thread (l,row): score dot
    {
      const float2* hr2 = (const float2*)(&h_s[row * 258]);
      const float2* qr2 = (const float2*)(&qk_s[l * 256]);
      float acc = 0.f;
#pragma unroll 8
      for (int e = 0; e < 128; ++e) {
        float2 hv = hr2[e], qv = qr2[e];
        acc += hv.x * qv.x + hv.y * qv.y;
      }
      float ev = __expf(acc * 0.0625f);  // scale = 1/sqrt(256); no max-sub needed (|s| small)
      e_s[tid] = ev;                     // e_s[l*32+row]
      dloc += ev;
      beta_out[(((long)b * KK + t) * Ln + l) * Nn + tile * 64 + sub * 32 + row] = ev;
    }
    __syncthreads();
    // phase B: thread = d: av[l] += e[l,row] * h[row,d]
    for (int rr = 0; rr < 32; ++rr) {
      float hv = h_s[rr * 258 + tid];
#pragma unroll
      for (int i = 0; i < 8; ++i) av[i] += e_s[i * 32 + rr] * hv;
    }
  }
  long pbase = (long)(b * 16 + tile) * 2048;
#pragma unroll
  for (int i = 0; i < 8; ++i) par_av[pbase + i * 256 + tid] = av[i];
  red[tid] = dloc;
  __syncthreads();
  if (tid < 8) {
    float s = 0.f;
    for (int i = 0; i < 32; ++i) s += red[tid * 32 + i];
    par_den[(b * 16 + tile) * 8 + tid] = s;
  }
}

// Reduce partials; GRU fused via Wgi (6 dots -> s2 directly); Beta normalize.
__global__ __launch_bounds__(256) void s2_kernel(
    const float* __restrict__ Wgi, const float* __restrict__ bgi,
    const float* __restrict__ Whh, const float* __restrict__ bhh,
    const float* __restrict__ par_av, const float* __restrict__ par_den,
    const float* __restrict__ slots, float* __restrict__ s2out,
    float* __restrict__ beta, float* __restrict__ xsum, float* __restrict__ xsq, int t) {
  __shared__ float ah_s[2048], sl_s[2048];
  __shared__ float den_s[8];
  int j = blockIdx.x & 7, b = blockIdx.x >> 3, tid = threadIdx.x;
  for (int k = 0; k < 8; ++k) {
    int idx = tid + k * 256;
    float s = 0.f;
    long base = (long)b * 16 * 2048 + idx;
#pragma unroll
    for (int tl = 0; tl < 16; ++tl) s += par_av[base + tl * 2048];
    ah_s[idx] = s;
    sl_s[idx] = slots[b * 2048 + idx];
  }
  if (tid < 8) {
    float s = 0.f;
    for (int tl = 0; tl < 16; ++tl) s += par_den[(b * 16 + tl) * 8 + tid];
    den_s[tid] = 1.f / s;
  }
  if (j == 0 && tid < 8) { xsum[b * 8 + tid] = 0.f; xsq[b * 8 + tid] = 0.f; }
  __syncthreads();
  int l = tid >> 5, dd = j * 32 + (tid & 31);
  float rden = den_s[l];
  const float2* a2 = (const float2*)(&ah_s[l * 256]);
  const float2* s2p = (const float2*)(&sl_s[l * 256]);
  const float2* wr_r = (const float2*)(Wgi + dd * 256);
  const float2* wr_z = (const float2*)(Wgi + 65536 + dd * 256);
  const float2* wr_n = (const float2*)(Wgi + 131072 + dd * 256);
  const float2* wh_r = (const float2*)(Whh + dd * 256);
  const float2* wh_z = (const float2*)(Whh + 65536 + dd * 256);
  const float2* wh_n = (const float2*)(Whh + 131072 + dd * 256);
  float ir = 0, iz = 0, in_ = 0, hr = 0, hz = 0, hn = 0;
#pragma unroll 4
  for (int e = 0; e < 128; ++e) {
    float2 a = a2[e], s = s2p[e], w;
    w = wr_r[e]; ir += a.x * w.x + a.y * w.y;
    w = wr_z[e]; iz += a.x * w.x + a.y * w.y;
    w = wr_n[e]; in_ += a.x * w.x + a.y * w.y;
    w = wh_r[e]; hr += s.x * w.x + s.y * w.y;
    w = wh_z[e]; hz += s.x * w.x + s.y * w.y;
    w = wh_n[e]; hn += s.x * w.x + s.y * w.y;
  }
  float irt = ir * rden + bgi[dd];
  float izt = iz * rden + bgi[256 + dd];
  float int_ = in_ * rden + bgi[512 + dd];
  float hrt = hr + bhh[dd], hzt = hz + bhh[256 + dd], hnt = hn + bhh[512 + dd];
  float r = 1.f / (1.f + __expf(-(irt + hrt)));
  float z = 1.f / (1.f + __expf(-(izt + hzt)));
  float n = tanhf(int_ + r * hnt);
  s2out[b * 2048 + l * 256 + dd] = (1.f - z) * n + z * sl_s[l * 256 + dd];
  // Beta normalize: wg j handles slot l=j of this b
  float rd = den_s[j];
  long bb = (((long)b * KK + t) * Ln + j) * Nn;
  for (int k = 0; k < 4; ++k) beta[bb + tid + k * 256] *= rd;
}

__global__ __launch_bounds__(256) void f1_kernel(
    const float* __restrict__ W1, const float* __restrict__ b1,
    const float* __restrict__ s2, float* __restrict__ f1) {
  __shared__ float s_s[2048];
  int j = blockIdx.x & 7, b = blockIdx.x >> 3, tid = threadIdx.x;
  for (int k = 0; k < 8; ++k) s_s[tid + k * 256] = s2[b * 2048 + tid + k * 256];
  __syncthreads();
  int l = tid >> 5, dd = j * 32 + (tid & 31);
  const float2* w = (const float2*)(W1 + dd * 256);
  const float2* x = (const float2*)(&s_s[l * 256]);
  float acc = 0.f;
#pragma unroll 8
  for (int e = 0; e < 128; ++e) { float2 wv = w[e], xv = x[e]; acc += wv.x * xv.x + wv.y * xv.y; }
  f1[b * 2048 + l * 256 + dd] = fmaxf(acc + b1[dd], 0.f);
}

__global__ __launch_bounds__(256) void ffn_kernel(
    const float* __restrict__ W2, const float* __restrict__ b2,
    const float* __restrict__ s2, const float* __restrict__ f1,
    float* __restrict__ xout, float* __restrict__ xsum, float* __restrict__ xsq) {
  __shared__ float f_s[2048];
  __shared__ float red[256], red2[256];
  int j = blockIdx.x & 7, b = blockIdx.x >> 3, tid = threadIdx.x;
  for (int k = 0; k < 8; ++k) f_s[tid + k * 256] = f1[b * 2048 + tid + k * 256];
  __syncthreads();
  int l = tid >> 5, dd = j * 32 + (tid & 31);
  const float2* w = (const float2*)(W2 + dd * 256);
  const float2* ff = (const float2*)(&f_s[l * 256]);
  float acc = 0.f;
#pragma unroll 8
  for (int e = 0; e < 128; ++e) { float2 wv = w[e], fv = ff[e]; acc += wv.x * fv.x + wv.y * fv.y; }
  float xv = s2[b * 2048 + l * 256 + dd] + acc + b2[dd];
  xout[b * 2048 + l * 256 + dd] = xv;
  red[tid] = xv;
  red2[tid] = xv * xv;
  __syncthreads();
  if (tid < 8) {
    float s = 0.f, sq = 0.f;
    for (int i = 0; i < 32; ++i) { s += red[tid * 32 + i]; sq += red2[tid * 32 + i]; }
    atomicAdd(&xsum[b * 8 + tid], s);
    atomicAdd(&xsq[b * 8 + tid], sq);
  }
}

// LayerNorm -> s3 (write S + slots) and next-step Qk = s3@Wqk + bqk
__global__ __launch_bounds__(256) void ln_qk_kernel(
    const float* __restrict__ Wqk, const float* __restrict__ bqk,
    const float* __restrict__ x, const float* __restrict__ xsum,
    const float* __restrict__ xsq, const float* __restrict__ ln_g,
    const float* __restrict__ ln_b, float* __restrict__ S,
    float* __restrict__ slots, float* __restrict__ Qkout, int t) {
  __shared__ float s3_s[2048];
  int j = blockIdx.x & 7, b = blockIdx.x >> 3, tid = threadIdx.x;
  for (int k = 0; k < 8; ++k) {
    int idx = tid + k * 256;
    int l = idx >> 8, d = idx & 255;
    float m = xsum[b * 8 + l] * (1.f / 256.f);
    float v = xsq[b * 8 + l] * (1.f / 256.f) - m * m;
    float rstd = rsqrtf(v + 1e-5f);
    float s3 = (x[b * 2048 + idx] - m) * rstd * ln_g[d] + ln_b[d];
    s3_s[idx] = s3;
    if (k == j) {  // each wg writes a distinct 256-chunk
      S[((long)b * KK + t) * 2048 + idx] = s3;
      slots[b * 2048 + idx] = s3;
    }
  }
  __syncthreads();
  int l = tid >> 5, ee = j * 32 + (tid & 31);
  float acc = bqk[ee];
  for (int d = 0; d < 256; ++d) acc += s3_s[l * 256 + d] * Wqk[d * 256 + ee];
  Qkout[b * 2048 + l * 256 + ee] = acc;
}

extern "C" void kernel_launch(void* const* d_in, const int* in_sizes, int n_in,
                              void* d_out, int out_size, void* d_ws, size_t ws_size,
                              hipStream_t stream) {
  const float* H    = (const float*)d_in[0];
  const float* eps  = (const float*)d_in[1];
  const float* mu   = (const float*)d_in[2];
  const float* lsig = (const float*)d_in[3];
  const float* Wq   = (const float*)d_in[4];
  const float* bq   = (const float*)d_in[5];
  const float* Wk   = (const float*)d_in[6];
  // d_in[7] = bk: drops out of softmax (constant per row) -> unused
  const float* Wv   = (const float*)d_in[8];
  const float* bv   = (const float*)d_in[9];
  const float* Wih  = (const float*)d_in[10];
  const float* bih  = (const float*)d_in[11];
  const float* Whh  = (const float*)d_in[12];
  const float* bhh  = (const float*)d_in[13];
  const float* W1   = (const float*)d_in[14];
  const float* b1   = (const float*)d_in[15];
  const float* W2   = (const float*)d_in[16];
  const float* b2   = (const float*)d_in[17];
  const float* ln_g = (const float*)d_in[18];
  const float* ln_b = (const float*)d_in[19];

  float* out = (float*)d_out;
  float* S    = out;                       // [B,K,L,D] = 524288
  float* Beta = out + (long)Bn * KK * Ln * Dn;  // [B,K,L,N] = 2097152

  float* ws = (float*)d_ws;
  float* Wqk  = ws + OFF_WQK;
  float* bqk  = ws + OFF_BQK;
  float* Wgi  = ws + OFF_WGI;
  float* bgi  = ws + OFF_BGI;
  float* slots = ws + OFF_SLOTS;
  float* Qk   = ws + OFF_QK;
  float* pav  = ws + OFF_PAV;
  float* pden = ws + OFF_PDEN;
  float* s2b  = ws + OFF_S2;
  float* f1b  = ws + OFF_F1;
  float* xb   = ws + OFF_X;
  float* xsum = ws + OFF_XSUM;
  float* xsq  = ws + OFF_XSQ;

  precompute_kernel<<<1025, 256, 0, stream>>>(Wq, bq, Wk, Wih, bih, Wv, bv, Wqk, bqk, Wgi, bgi);
  init_slots_kernel<<<128, 256, 0, stream>>>(eps, mu, lsig, slots);
  qk0_kernel<<<128, 256, 0, stream>>>(Wqk, bqk, slots, Qk);

  for (int t = 0; t < KK; ++t) {
    attn_kernel<<<dim3(16, 16), 256, 0, stream>>>(H, Qk, Beta, pav, pden, t);
    s2_kernel<<<128, 256, 0, stream>>>(Wgi, bgi, Whh, bhh, pav, pden, slots, s2b, Beta, xsum, xsq, t);
    f1_kernel<<<128, 256, 0, stream>>>(W1, b1, s2b, f1b);
    ffn_kernel<<<128, 256, 0, stream>>>(W2, b2, s2b, f1b, xb, xsum, xsq);
    ln_qk_kernel<<<128, 256, 0, stream>>>(Wqk, bqk, xb, xsum, xsq, ln_g, ln_b, S, slots, Qk, t);
  }
}